// Round 7
// baseline (298.257 us; speedup 1.0000x reference)
//
#include <hip/hip_runtime.h>
#include <math.h>

constexpr int N_NODES  = 100000;
constexpr int N_EDGES  = 3200000;
constexpr int N_GRAPHS = 512;
constexpr int FEAT = 128;
constexpr int H1 = 32;
constexpr int H2 = 16;
constexpr int NCLS = 10;
constexpr int NBUCKET = (N_NODES + 255) / 256;          // 391 buckets of 256 nodes
constexpr int CHUNK   = 8192;                           // edges per bin block
constexpr int NBINBLK = (N_EDGES + CHUNK - 1) / CHUNK;  // 391
constexpr int CAP     = 10240;   // bucket capacity; mean 8184, sigma 90 -> 23 sigma slack
constexpr int SRCMASK = 0x1FFFF;                        // 17 bits (100000 < 131072)

// ---- init: bucket cursors at fixed bases; zero pooled sums/counts ----------
__global__ void k_init(int* __restrict__ bcur, float* __restrict__ psum,
                       float* __restrict__ pcnt) {
    int i = blockIdx.x * 256 + threadIdx.x;
    if (i < NBUCKET) bcur[i] = i * CAP;
    if (i < N_GRAPHS * H2) psum[i] = 0.0f;
    if (i < N_GRAPHS) pcnt[i] = 0.0f;
}

// ---- radix partition: LDS-reorder 8192 edges, burst-write bucket runs ------
__global__ __launch_bounds__(512)
void k_bin(const int* __restrict__ src, const int* __restrict__ dst,
           int* __restrict__ bcur, int* __restrict__ ebkt) {
    __shared__ int val_s[CHUNK];
    __shared__ int adr_s[CHUNK];
    __shared__ int hist[NBUCKET];
    __shared__ int excl[NBUCKET];
    __shared__ int curb[NBUCKET];
    __shared__ int runb[NBUCKET];
    __shared__ int ss[512];
    int tid = threadIdx.x;
    int base = blockIdx.x * CHUNK;
    int cntblk = N_EDGES - base; if (cntblk > CHUNK) cntblk = CHUNK;
    for (int i = tid; i < NBUCKET; i += 512) hist[i] = 0;
    __syncthreads();
    for (int e = tid; e < cntblk; e += 512)
        atomicAdd(&hist[dst[base + e] >> 8], 1);
    __syncthreads();
    int v = (tid < NBUCKET) ? hist[tid] : 0;
    ss[tid] = v;
    __syncthreads();
    for (int d = 1; d < 512; d <<= 1) {
        int t = (tid >= d) ? ss[tid - d] : 0;
        __syncthreads();
        ss[tid] += t;
        __syncthreads();
    }
    if (tid < NBUCKET) {
        int ex = ss[tid] - v;
        excl[tid] = ex;
        curb[tid] = ex;
        runb[tid] = atomicAdd(&bcur[tid], v);   // reserve this block's run
    }
    __syncthreads();
    for (int e = tid; e < cntblk; e += 512) {
        int d = dst[base + e];
        int srcv = src[base + e];
        int b = d >> 8;
        int q = atomicAdd(&curb[b], 1);
        val_s[q] = srcv | ((d & 255) << 17);
        adr_s[q] = runb[b] + (q - excl[b]);
    }
    __syncthreads();
    for (int q = tid; q < cntblk; q += 512)
        ebkt[adr_s[q]] = val_s[q];
}

// ---- per-bucket placement: node hist+scan in LDS, exclusive region ---------
__global__ void k_place3(const int* __restrict__ bcur, const int* __restrict__ ebkt,
                         int* __restrict__ start_g, int* __restrict__ cnt_g,
                         float* __restrict__ dinv, int* __restrict__ esrc) {
    __shared__ int hist[256];
    __shared__ int cur[256];
    __shared__ int ss[256];
    int b = blockIdx.x;
    int tid = threadIdx.x;
    int nbase = b << 8;
    int ebase = b * CAP;
    int eend  = bcur[b];          // base + bucket count (after k_bin)
    hist[tid] = 0;
    __syncthreads();
    for (int e = ebase + tid; e < eend; e += 256)
        atomicAdd(&hist[(ebkt[e] >> 17) & 255], 1);
    __syncthreads();
    int v = hist[tid];
    ss[tid] = v;
    __syncthreads();
    for (int d = 1; d < 256; d <<= 1) {
        int t = (tid >= d) ? ss[tid - d] : 0;
        __syncthreads();
        ss[tid] += t;
        __syncthreads();
    }
    int st = ebase + ss[tid] - v;
    cur[tid] = st;
    int node = nbase + tid;
    if (node < N_NODES) {
        start_g[node] = st;
        cnt_g[node] = v;
        dinv[node] = rsqrtf((float)v + 1.0f);   // +1 self loop
    }
    __syncthreads();
    for (int e = ebase + tid; e < eend; e += 256) {
        int p = ebkt[e];
        int pos = atomicAdd(&cur[(p >> 17) & 255], 1);
        esrc[pos] = p & SRCMASK;
    }
}

// ---- layer1 GEMM: h1s = (X @ W1) * dinv[i] ---------------------------------
__global__ void k_gemm1(const float* __restrict__ X, const float* __restrict__ W1,
                        const float* __restrict__ dinv, float* __restrict__ h1s) {
    int i = blockIdx.x * 256 + threadIdx.x;
    if (i >= N_NODES) return;
    float acc[H1];
#pragma unroll
    for (int j = 0; j < H1; ++j) acc[j] = 0.0f;
    const float4* xr = (const float4*)(X + (size_t)i * FEAT);
    for (int kc = 0; kc < FEAT / 4; ++kc) {
        float4 xv = xr[kc];
        const float* w = W1 + (kc * 4) * H1;   // wave-uniform -> scalar loads
#pragma unroll
        for (int j = 0; j < H1; ++j)
            acc[j] += xv.x * w[j] + xv.y * w[H1 + j]
                    + xv.z * w[2 * H1 + j] + xv.w * w[3 * H1 + j];
    }
    float di = dinv[i];
    float4* hp = (float4*)(h1s + (size_t)i * H1);
#pragma unroll
    for (int q = 0; q < H1 / 4; ++q)
        hp[q] = make_float4(acc[q*4] * di, acc[q*4+1] * di,
                            acc[q*4+2] * di, acc[q*4+3] * di);
}

// ---- fused gather1 + bias/relu + gemm2 -------------------------------------
// 8 lanes/node. Chunk-16 MLP: two coalesced esrc dwords/lane, width-8 shfl
// broadcast, 16 row-loads in flight, single wait, adds. Next chunk's esrc
// prefetched before the row waits.
__global__ void k_gA(const int* __restrict__ start_g, const int* __restrict__ cnt_g,
                     const int* __restrict__ esrc, const float* __restrict__ h1s,
                     const float* __restrict__ b1, const float* __restrict__ W2,
                     const float* __restrict__ dinv, float* __restrict__ h2s) {
    int t = blockIdx.x * 256 + threadIdx.x;
    int node = t >> 3;            // grid sized exactly
    int lane = t & 7;
    int beg = start_g[node];
    int cnt = cnt_g[node];
    const float4* base = (const float4*)h1s;
    float4 a = base[(size_t)node * 8 + lane];   // self loop
    int n16 = cnt >> 4;
    int tail = cnt & 15;
    int n8 = tail >> 3;           // 0 or 1
    int rem = tail & 7;
    int ev0 = 0, ev1 = 0;
    if (n16 > 0) { ev0 = esrc[beg + lane]; ev1 = esrc[beg + 8 + lane]; }
    for (int c = 0; c < n16; ++c) {
        int e0n = 0, e1n = 0;   // prefetch next chunk before waiting on rows
        if (c + 1 < n16) {
            e0n = esrc[beg + (c + 1) * 16 + lane];
            e1n = esrc[beg + (c + 1) * 16 + 8 + lane];
        }
        float4 v0 = base[(size_t)__shfl(ev0, 0, 8) * 8 + lane];
        float4 v1 = base[(size_t)__shfl(ev0, 1, 8) * 8 + lane];
        float4 v2 = base[(size_t)__shfl(ev0, 2, 8) * 8 + lane];
        float4 v3 = base[(size_t)__shfl(ev0, 3, 8) * 8 + lane];
        float4 v4 = base[(size_t)__shfl(ev0, 4, 8) * 8 + lane];
        float4 v5 = base[(size_t)__shfl(ev0, 5, 8) * 8 + lane];
        float4 v6 = base[(size_t)__shfl(ev0, 6, 8) * 8 + lane];
        float4 v7 = base[(size_t)__shfl(ev0, 7, 8) * 8 + lane];
        float4 w0 = base[(size_t)__shfl(ev1, 0, 8) * 8 + lane];
        float4 w1 = base[(size_t)__shfl(ev1, 1, 8) * 8 + lane];
        float4 w2 = base[(size_t)__shfl(ev1, 2, 8) * 8 + lane];
        float4 w3 = base[(size_t)__shfl(ev1, 3, 8) * 8 + lane];
        float4 w4 = base[(size_t)__shfl(ev1, 4, 8) * 8 + lane];
        float4 w5 = base[(size_t)__shfl(ev1, 5, 8) * 8 + lane];
        float4 w6 = base[(size_t)__shfl(ev1, 6, 8) * 8 + lane];
        float4 w7 = base[(size_t)__shfl(ev1, 7, 8) * 8 + lane];
        a.x += (((v0.x + v1.x) + (v2.x + v3.x)) + ((v4.x + v5.x) + (v6.x + v7.x)))
             + (((w0.x + w1.x) + (w2.x + w3.x)) + ((w4.x + w5.x) + (w6.x + w7.x)));
        a.y += (((v0.y + v1.y) + (v2.y + v3.y)) + ((v4.y + v5.y) + (v6.y + v7.y)))
             + (((w0.y + w1.y) + (w2.y + w3.y)) + ((w4.y + w5.y) + (w6.y + w7.y)));
        a.z += (((v0.z + v1.z) + (v2.z + v3.z)) + ((v4.z + v5.z) + (v6.z + v7.z)))
             + (((w0.z + w1.z) + (w2.z + w3.z)) + ((w4.z + w5.z) + (w6.z + w7.z)));
        a.w += (((v0.w + v1.w) + (v2.w + v3.w)) + ((v4.w + v5.w) + (v6.w + v7.w)))
             + (((w0.w + w1.w) + (w2.w + w3.w)) + ((w4.w + w5.w) + (w6.w + w7.w)));
        ev0 = e0n; ev1 = e1n;
    }
    int tb = beg + n16 * 16;
    if (n8) {
        int ev = esrc[tb + lane];
        float4 v0 = base[(size_t)__shfl(ev, 0, 8) * 8 + lane];
        float4 v1 = base[(size_t)__shfl(ev, 1, 8) * 8 + lane];
        float4 v2 = base[(size_t)__shfl(ev, 2, 8) * 8 + lane];
        float4 v3 = base[(size_t)__shfl(ev, 3, 8) * 8 + lane];
        float4 v4 = base[(size_t)__shfl(ev, 4, 8) * 8 + lane];
        float4 v5 = base[(size_t)__shfl(ev, 5, 8) * 8 + lane];
        float4 v6 = base[(size_t)__shfl(ev, 6, 8) * 8 + lane];
        float4 v7 = base[(size_t)__shfl(ev, 7, 8) * 8 + lane];
        a.x += ((v0.x + v1.x) + (v2.x + v3.x)) + ((v4.x + v5.x) + (v6.x + v7.x));
        a.y += ((v0.y + v1.y) + (v2.y + v3.y)) + ((v4.y + v5.y) + (v6.y + v7.y));
        a.z += ((v0.z + v1.z) + (v2.z + v3.z)) + ((v4.z + v5.z) + (v6.z + v7.z));
        a.w += ((v0.w + v1.w) + (v2.w + v3.w)) + ((v4.w + v5.w) + (v6.w + v7.w));
        tb += 8;
    }
    if (rem) {
        int ev = (lane < rem) ? esrc[tb + lane] : 0;
#pragma unroll
        for (int j = 0; j < 8; ++j) {
            int sj = __shfl(ev, j, 8);
            bool val = (j < rem);
            float4 v = base[(size_t)(val ? sj : node) * 8 + lane];  // node row: L1-hot
            float m = val ? 1.0f : 0.0f;
            a.x += v.x * m; a.y += v.y * m; a.z += v.z * m; a.w += v.w * m;
        }
    }
    float di = dinv[node];
    // layer-1 epilogue: dst-side norm + bias + relu
    float x0 = fmaxf(a.x * di + b1[4*lane+0], 0.0f);
    float x1 = fmaxf(a.y * di + b1[4*lane+1], 0.0f);
    float x2 = fmaxf(a.z * di + b1[4*lane+2], 0.0f);
    float x3 = fmaxf(a.w * di + b1[4*lane+3], 0.0f);
    // per-lane partial of x @ W2 over my 4 k's
    float acc[H2];
    const float* q0 = W2 + (4*lane+0) * H2;
    const float* q1 = W2 + (4*lane+1) * H2;
    const float* q2 = W2 + (4*lane+2) * H2;
    const float* q3 = W2 + (4*lane+3) * H2;
#pragma unroll
    for (int j = 0; j < H2; ++j)
        acc[j] = x0 * q0[j] + x1 * q1[j] + x2 * q2[j] + x3 * q3[j];
    // shuffle-tree reduce, splitting feature ownership each step
    float p16[16];
#pragma unroll
    for (int j = 0; j < 16; ++j) p16[j] = __shfl_xor(acc[j], 1);
    float r8[8];
    if (lane & 1) {
#pragma unroll
        for (int j = 0; j < 8; ++j) r8[j] = acc[8+j] + p16[8+j];
    } else {
#pragma unroll
        for (int j = 0; j < 8; ++j) r8[j] = acc[j] + p16[j];
    }
    float p8[8];
#pragma unroll
    for (int j = 0; j < 8; ++j) p8[j] = __shfl_xor(r8[j], 2);
    float r4[4];
    if (lane & 2) {
#pragma unroll
        for (int j = 0; j < 4; ++j) r4[j] = r8[4+j] + p8[4+j];
    } else {
#pragma unroll
        for (int j = 0; j < 4; ++j) r4[j] = r8[j] + p8[j];
    }
    float p4[4];
#pragma unroll
    for (int j = 0; j < 4; ++j) p4[j] = __shfl_xor(r4[j], 4);
    float r2[2];
    if (lane & 4) {
        r2[0] = r4[2] + p4[2]; r2[1] = r4[3] + p4[3];
    } else {
        r2[0] = r4[0] + p4[0]; r2[1] = r4[1] + p4[1];
    }
    int fb = ((lane & 1) << 3) | (((lane >> 1) & 1) << 2) | (((lane >> 2) & 1) << 1);
    *(float2*)(h2s + (size_t)node * H2 + fb) = make_float2(r2[0] * di, r2[1] * di);
}

// ---- fused gather2 + bias/relu + mean-pool ---------------------------------
// 8 lanes/node, float2 slice each; chunk-16 MLP as in k_gA; sorted batch ->
// wave (8 nodes) usually one graph: butterfly reduce, 16+1 atomics/wave.
__global__ void k_gB(const int* __restrict__ start_g, const int* __restrict__ cnt_g,
                     const int* __restrict__ esrc, const float* __restrict__ h2s,
                     const float* __restrict__ b2, const float* __restrict__ dinv,
                     const int* __restrict__ batch,
                     float* __restrict__ psum, float* __restrict__ pcnt) {
    int t = blockIdx.x * 256 + threadIdx.x;
    int node = t >> 3;            // grid sized exactly
    int lane = t & 7;
    int beg = start_g[node];
    int cnt = cnt_g[node];
    const float2* base = (const float2*)h2s;
    float2 a = base[(size_t)node * 8 + lane];   // self loop
    int n16 = cnt >> 4;
    int tail = cnt & 15;
    int n8 = tail >> 3;
    int rem = tail & 7;
    int ev0 = 0, ev1 = 0;
    if (n16 > 0) { ev0 = esrc[beg + lane]; ev1 = esrc[beg + 8 + lane]; }
    for (int c = 0; c < n16; ++c) {
        int e0n = 0, e1n = 0;
        if (c + 1 < n16) {
            e0n = esrc[beg + (c + 1) * 16 + lane];
            e1n = esrc[beg + (c + 1) * 16 + 8 + lane];
        }
        float2 v0 = base[(size_t)__shfl(ev0, 0, 8) * 8 + lane];
        float2 v1 = base[(size_t)__shfl(ev0, 1, 8) * 8 + lane];
        float2 v2 = base[(size_t)__shfl(ev0, 2, 8) * 8 + lane];
        float2 v3 = base[(size_t)__shfl(ev0, 3, 8) * 8 + lane];
        float2 v4 = base[(size_t)__shfl(ev0, 4, 8) * 8 + lane];
        float2 v5 = base[(size_t)__shfl(ev0, 5, 8) * 8 + lane];
        float2 v6 = base[(size_t)__shfl(ev0, 6, 8) * 8 + lane];
        float2 v7 = base[(size_t)__shfl(ev0, 7, 8) * 8 + lane];
        float2 w0 = base[(size_t)__shfl(ev1, 0, 8) * 8 + lane];
        float2 w1 = base[(size_t)__shfl(ev1, 1, 8) * 8 + lane];
        float2 w2 = base[(size_t)__shfl(ev1, 2, 8) * 8 + lane];
        float2 w3 = base[(size_t)__shfl(ev1, 3, 8) * 8 + lane];
        float2 w4 = base[(size_t)__shfl(ev1, 4, 8) * 8 + lane];
        float2 w5 = base[(size_t)__shfl(ev1, 5, 8) * 8 + lane];
        float2 w6 = base[(size_t)__shfl(ev1, 6, 8) * 8 + lane];
        float2 w7 = base[(size_t)__shfl(ev1, 7, 8) * 8 + lane];
        a.x += (((v0.x + v1.x) + (v2.x + v3.x)) + ((v4.x + v5.x) + (v6.x + v7.x)))
             + (((w0.x + w1.x) + (w2.x + w3.x)) + ((w4.x + w5.x) + (w6.x + w7.x)));
        a.y += (((v0.y + v1.y) + (v2.y + v3.y)) + ((v4.y + v5.y) + (v6.y + v7.y)))
             + (((w0.y + w1.y) + (w2.y + w3.y)) + ((w4.y + w5.y) + (w6.y + w7.y)));
        ev0 = e0n; ev1 = e1n;
    }
    int tb = beg + n16 * 16;
    if (n8) {
        int ev = esrc[tb + lane];
        float2 v0 = base[(size_t)__shfl(ev, 0, 8) * 8 + lane];
        float2 v1 = base[(size_t)__shfl(ev, 1, 8) * 8 + lane];
        float2 v2 = base[(size_t)__shfl(ev, 2, 8) * 8 + lane];
        float2 v3 = base[(size_t)__shfl(ev, 3, 8) * 8 + lane];
        float2 v4 = base[(size_t)__shfl(ev, 4, 8) * 8 + lane];
        float2 v5 = base[(size_t)__shfl(ev, 5, 8) * 8 + lane];
        float2 v6 = base[(size_t)__shfl(ev, 6, 8) * 8 + lane];
        float2 v7 = base[(size_t)__shfl(ev, 7, 8) * 8 + lane];
        a.x += ((v0.x + v1.x) + (v2.x + v3.x)) + ((v4.x + v5.x) + (v6.x + v7.x));
        a.y += ((v0.y + v1.y) + (v2.y + v3.y)) + ((v4.y + v5.y) + (v6.y + v7.y));
        tb += 8;
    }
    if (rem) {
        int ev = (lane < rem) ? esrc[tb + lane] : 0;
#pragma unroll
        for (int j = 0; j < 8; ++j) {
            int sj = __shfl(ev, j, 8);
            bool val = (j < rem);
            float2 v = base[(size_t)(val ? sj : node) * 8 + lane];
            float m = val ? 1.0f : 0.0f;
            a.x += v.x * m; a.y += v.y * m;
        }
    }
    float di = dinv[node];
    float vx = fmaxf(a.x * di + b2[2*lane+0], 0.0f);
    float vy = fmaxf(a.y * di + b2[2*lane+1], 0.0f);
    float c = (lane == 0) ? 1.0f : 0.0f;
    int g = batch[node];
    int wl = threadIdx.x & 63;
    int g0 = __shfl(g, 0);
    bool uni = (__ballot(g == g0) == ~0ull);
    if (uni) {
#pragma unroll
        for (int m = 8; m <= 32; m <<= 1) {
            vx += __shfl_xor(vx, m);
            vy += __shfl_xor(vy, m);
            c  += __shfl_xor(c, m);
        }
        if (wl < 8) {
            unsafeAtomicAdd(&psum[g0 * H2 + 2*wl + 0], vx);
            unsafeAtomicAdd(&psum[g0 * H2 + 2*wl + 1], vy);
        }
        if (wl == 0) unsafeAtomicAdd(&pcnt[g0], c);
    } else {
        unsafeAtomicAdd(&psum[g * H2 + 2*lane + 0], vx);
        unsafeAtomicAdd(&psum[g * H2 + 2*lane + 1], vy);
        if (lane == 0) unsafeAtomicAdd(&pcnt[g], 1.0f);
    }
}

// ---- head: mean, fc, softmax ------------------------------------------------
__global__ void k_head(const float* __restrict__ psum, const float* __restrict__ pcnt,
                       const float* __restrict__ fcw, const float* __restrict__ fcb,
                       float* __restrict__ out) {
    int g = blockIdx.x * 256 + threadIdx.x;
    if (g >= N_GRAPHS) return;
    float inv = 1.0f / fmaxf(pcnt[g], 1.0f);
    float p[H2];
#pragma unroll
    for (int j = 0; j < H2; ++j) p[j] = psum[g * H2 + j] * inv;
    float lg[NCLS];
    float m = -1e30f;
#pragma unroll
    for (int c = 0; c < NCLS; ++c) {
        float s = fcb[c];
#pragma unroll
        for (int j = 0; j < H2; ++j) s += p[j] * fcw[j * NCLS + c];
        lg[c] = s;
        m = fmaxf(m, s);
    }
    float sum = 0.0f;
#pragma unroll
    for (int c = 0; c < NCLS; ++c) { lg[c] = expf(lg[c] - m); sum += lg[c]; }
    float is = 1.0f / sum;
#pragma unroll
    for (int c = 0; c < NCLS; ++c) out[g * NCLS + c] = lg[c] * is;
}

extern "C" void kernel_launch(void* const* d_in, const int* in_sizes, int n_in,
                              void* d_out, int out_size, void* d_ws, size_t ws_size,
                              hipStream_t stream) {
    const float* X   = (const float*)d_in[0];
    const int*   ei  = (const int*)d_in[1];
    const int*   bat = (const int*)d_in[2];
    const float* W1  = (const float*)d_in[3];
    const float* b1  = (const float*)d_in[4];
    const float* W2  = (const float*)d_in[5];
    const float* b2  = (const float*)d_in[6];
    const float* fcw = (const float*)d_in[7];
    const float* fcb = (const float*)d_in[8];
    float* out = (float*)d_out;

    const int* src = ei;
    const int* dst = ei + N_EDGES;

    char* ws = (char*)d_ws;
    int*   bcur  = (int*)ws;    ws += 512 * 4;
    int*   startg= (int*)ws;    ws += (size_t)N_NODES * 4;
    int*   cntg  = (int*)ws;    ws += (size_t)N_NODES * 4;
    float* dinv  = (float*)ws;  ws += (size_t)N_NODES * 4;
    int*   esrc  = (int*)ws;    ws += (size_t)NBUCKET * CAP * 4;   // 16 MB, gapped CSR
    float* h1s   = (float*)ws;  ws += (size_t)N_NODES * H1 * 4;    // 12.8 MB
    float* h2s   = (float*)ws;  ws += (size_t)N_NODES * H2 * 4;    // 6.4 MB
    float* psum  = (float*)ws;  ws += (size_t)N_GRAPHS * H2 * 4;
    float* pcnt  = (float*)ws;
    // ebkt (16 MB) aliases h1s+h2s (19.2 MB): dead before k_gemm1/k_gA write them
    int* ebkt = (int*)h1s;

    int nbN = (N_NODES + 255) / 256;

    k_init  <<<32, 256, 0, stream>>>(bcur, psum, pcnt);
    k_bin   <<<NBINBLK, 512, 0, stream>>>(src, dst, bcur, ebkt);
    k_place3<<<NBUCKET, 256, 0, stream>>>(bcur, ebkt, startg, cntg, dinv, esrc);
    k_gemm1 <<<nbN, 256, 0, stream>>>(X, W1, dinv, h1s);
    k_gA    <<<(N_NODES * 8) / 256, 256, 0, stream>>>(startg, cntg, esrc, h1s, b1, W2, dinv, h2s);
    k_gB    <<<(N_NODES * 8) / 256, 256, 0, stream>>>(startg, cntg, esrc, h2s, b2, dinv, bat, psum, pcnt);
    k_head  <<<(N_GRAPHS + 255) / 256, 256, 0, stream>>>(psum, pcnt, fcw, fcb, out);
}

// Round 8
// 280.534 us; speedup vs baseline: 1.0632x; 1.0632x over previous
//
#include <hip/hip_runtime.h>
#include <hip/hip_fp16.h>
#include <math.h>

constexpr int N_NODES  = 100000;
constexpr int N_EDGES  = 3200000;
constexpr int N_GRAPHS = 512;
constexpr int FEAT = 128;
constexpr int H1 = 32;
constexpr int H2 = 16;
constexpr int NCLS = 10;
constexpr int NBUCKET = (N_NODES + 255) / 256;          // 391 buckets of 256 nodes
constexpr int CHUNK   = 8192;                           // edges per bin block
constexpr int NBINBLK = (N_EDGES + CHUNK - 1) / CHUNK;  // 391
constexpr int CAP     = 10240;   // bucket capacity; mean 8184, sigma 90 -> 23 sigma slack
constexpr int SRCMASK = 0x1FFFF;                        // 17 bits (100000 < 131072)

__device__ __forceinline__ float4 cvt84(uint2 u) {
    float2 f0 = __half22float2(*reinterpret_cast<__half2*>(&u.x));
    float2 f1 = __half22float2(*reinterpret_cast<__half2*>(&u.y));
    return make_float4(f0.x, f0.y, f1.x, f1.y);
}
__device__ __forceinline__ float2 cvt42(unsigned u) {
    return __half22float2(*reinterpret_cast<__half2*>(&u));
}

// ---- init: bucket cursors at fixed bases; zero pooled sums/counts ----------
__global__ void k_init(int* __restrict__ bcur, float* __restrict__ psum,
                       float* __restrict__ pcnt) {
    int i = blockIdx.x * 256 + threadIdx.x;
    if (i < NBUCKET) bcur[i] = i * CAP;
    if (i < N_GRAPHS * H2) psum[i] = 0.0f;
    if (i < N_GRAPHS) pcnt[i] = 0.0f;
}

// ---- radix partition: LDS-reorder 8192 edges, burst-write bucket runs ------
__global__ __launch_bounds__(512)
void k_bin(const int* __restrict__ src, const int* __restrict__ dst,
           int* __restrict__ bcur, int* __restrict__ ebkt) {
    __shared__ int val_s[CHUNK];
    __shared__ int adr_s[CHUNK];
    __shared__ int hist[NBUCKET];
    __shared__ int excl[NBUCKET];
    __shared__ int curb[NBUCKET];
    __shared__ int runb[NBUCKET];
    __shared__ int ss[512];
    int tid = threadIdx.x;
    int base = blockIdx.x * CHUNK;
    int cntblk = N_EDGES - base; if (cntblk > CHUNK) cntblk = CHUNK;
    for (int i = tid; i < NBUCKET; i += 512) hist[i] = 0;
    __syncthreads();
    for (int e = tid; e < cntblk; e += 512)
        atomicAdd(&hist[dst[base + e] >> 8], 1);
    __syncthreads();
    int v = (tid < NBUCKET) ? hist[tid] : 0;
    ss[tid] = v;
    __syncthreads();
    for (int d = 1; d < 512; d <<= 1) {
        int t = (tid >= d) ? ss[tid - d] : 0;
        __syncthreads();
        ss[tid] += t;
        __syncthreads();
    }
    if (tid < NBUCKET) {
        int ex = ss[tid] - v;
        excl[tid] = ex;
        curb[tid] = ex;
        runb[tid] = atomicAdd(&bcur[tid], v);   // reserve this block's run
    }
    __syncthreads();
    for (int e = tid; e < cntblk; e += 512) {
        int d = dst[base + e];
        int srcv = src[base + e];
        int b = d >> 8;
        int q = atomicAdd(&curb[b], 1);
        val_s[q] = srcv | ((d & 255) << 17);
        adr_s[q] = runb[b] + (q - excl[b]);
    }
    __syncthreads();
    for (int q = tid; q < cntblk; q += 512)
        ebkt[adr_s[q]] = val_s[q];
}

// ---- per-bucket placement: node hist+scan in LDS, exclusive region ---------
__global__ void k_place3(const int* __restrict__ bcur, const int* __restrict__ ebkt,
                         int* __restrict__ start_g, int* __restrict__ cnt_g,
                         float* __restrict__ dinv, int* __restrict__ esrc) {
    __shared__ int hist[256];
    __shared__ int cur[256];
    __shared__ int ss[256];
    int b = blockIdx.x;
    int tid = threadIdx.x;
    int nbase = b << 8;
    int ebase = b * CAP;
    int eend  = bcur[b];          // base + bucket count (after k_bin)
    hist[tid] = 0;
    __syncthreads();
    for (int e = ebase + tid; e < eend; e += 256)
        atomicAdd(&hist[(ebkt[e] >> 17) & 255], 1);
    __syncthreads();
    int v = hist[tid];
    ss[tid] = v;
    __syncthreads();
    for (int d = 1; d < 256; d <<= 1) {
        int t = (tid >= d) ? ss[tid - d] : 0;
        __syncthreads();
        ss[tid] += t;
        __syncthreads();
    }
    int st = ebase + ss[tid] - v;
    cur[tid] = st;
    int node = nbase + tid;
    if (node < N_NODES) {
        start_g[node] = st;
        cnt_g[node] = v;
        dinv[node] = rsqrtf((float)v + 1.0f);   // +1 self loop
    }
    __syncthreads();
    for (int e = ebase + tid; e < eend; e += 256) {
        int p = ebkt[e];
        int pos = atomicAdd(&cur[(p >> 17) & 255], 1);
        esrc[pos] = p & SRCMASK;
    }
}

// ---- layer1 GEMM: h1s = fp16((X @ W1) * dinv[i]) ---------------------------
__global__ void k_gemm1(const float* __restrict__ X, const float* __restrict__ W1,
                        const float* __restrict__ dinv, __half* __restrict__ h1s) {
    int i = blockIdx.x * 256 + threadIdx.x;
    if (i >= N_NODES) return;
    float acc[H1];
#pragma unroll
    for (int j = 0; j < H1; ++j) acc[j] = 0.0f;
    const float4* xr = (const float4*)(X + (size_t)i * FEAT);
    for (int kc = 0; kc < FEAT / 4; ++kc) {
        float4 xv = xr[kc];
        const float* w = W1 + (kc * 4) * H1;   // wave-uniform -> scalar loads
#pragma unroll
        for (int j = 0; j < H1; ++j)
            acc[j] += xv.x * w[j] + xv.y * w[H1 + j]
                    + xv.z * w[2 * H1 + j] + xv.w * w[3 * H1 + j];
    }
    float di = dinv[i];
    __half2* hp = (__half2*)(h1s + (size_t)i * H1);
#pragma unroll
    for (int q = 0; q < H1 / 2; ++q)
        hp[q] = __floats2half2_rn(acc[2*q] * di, acc[2*q+1] * di);
}

// ---- fused gather1 + bias/relu + gemm2 -------------------------------------
// 8 lanes/node; lane owns feats 4q..4q+3 (8B of the 64B fp16 row). Chunk-8
// MLP: one coalesced esrc dword/lane, width-8 shfl broadcast, 8 row-loads in
// flight, single wait, cvt+adds. Next chunk's esrc prefetched early.
__global__ void k_gA(const int* __restrict__ start_g, const int* __restrict__ cnt_g,
                     const int* __restrict__ esrc, const __half* __restrict__ h1s,
                     const float* __restrict__ b1, const float* __restrict__ W2,
                     const float* __restrict__ dinv, __half* __restrict__ h2s) {
    int t = blockIdx.x * 256 + threadIdx.x;
    int node = t >> 3;            // grid sized exactly
    int lane = t & 7;
    int beg = start_g[node];
    int cnt = cnt_g[node];
    const uint2* base = (const uint2*)h1s;      // 8B granules, row = 8 granules
    float4 a = cvt84(base[(size_t)node * 8 + lane]);   // self loop
    int nfull = cnt >> 3;
    int rem = cnt & 7;
    int ev = (nfull > 0) ? esrc[beg + lane]
           : ((lane < rem) ? esrc[beg + lane] : 0);
    for (int c = 0; c < nfull; ++c) {
        int evn = 0;   // prefetch next chunk (or tail) before waiting on rows
        if (c + 1 < nfull) evn = esrc[beg + (c + 1) * 8 + lane];
        else if (lane < rem) evn = esrc[beg + nfull * 8 + lane];
        uint2 u0 = base[(size_t)__shfl(ev, 0, 8) * 8 + lane];
        uint2 u1 = base[(size_t)__shfl(ev, 1, 8) * 8 + lane];
        uint2 u2 = base[(size_t)__shfl(ev, 2, 8) * 8 + lane];
        uint2 u3 = base[(size_t)__shfl(ev, 3, 8) * 8 + lane];
        uint2 u4 = base[(size_t)__shfl(ev, 4, 8) * 8 + lane];
        uint2 u5 = base[(size_t)__shfl(ev, 5, 8) * 8 + lane];
        uint2 u6 = base[(size_t)__shfl(ev, 6, 8) * 8 + lane];
        uint2 u7 = base[(size_t)__shfl(ev, 7, 8) * 8 + lane];
        float4 v0 = cvt84(u0), v1 = cvt84(u1), v2 = cvt84(u2), v3 = cvt84(u3);
        float4 v4 = cvt84(u4), v5 = cvt84(u5), v6 = cvt84(u6), v7 = cvt84(u7);
        a.x += ((v0.x + v1.x) + (v2.x + v3.x)) + ((v4.x + v5.x) + (v6.x + v7.x));
        a.y += ((v0.y + v1.y) + (v2.y + v3.y)) + ((v4.y + v5.y) + (v6.y + v7.y));
        a.z += ((v0.z + v1.z) + (v2.z + v3.z)) + ((v4.z + v5.z) + (v6.z + v7.z));
        a.w += ((v0.w + v1.w) + (v2.w + v3.w)) + ((v4.w + v5.w) + (v6.w + v7.w));
        ev = evn;
    }
    if (rem) {
#pragma unroll
        for (int j = 0; j < 8; ++j) {
            int sj = __shfl(ev, j, 8);
            bool val = (j < rem);
            uint2 u = base[(size_t)(val ? sj : node) * 8 + lane];  // node row: L1-hot
            float4 v = cvt84(u);
            float m = val ? 1.0f : 0.0f;
            a.x += v.x * m; a.y += v.y * m; a.z += v.z * m; a.w += v.w * m;
        }
    }
    float di = dinv[node];
    // layer-1 epilogue: dst-side norm + bias + relu
    float x0 = fmaxf(a.x * di + b1[4*lane+0], 0.0f);
    float x1 = fmaxf(a.y * di + b1[4*lane+1], 0.0f);
    float x2 = fmaxf(a.z * di + b1[4*lane+2], 0.0f);
    float x3 = fmaxf(a.w * di + b1[4*lane+3], 0.0f);
    // per-lane partial of x @ W2 over my 4 k's
    float acc[H2];
    const float* q0 = W2 + (4*lane+0) * H2;
    const float* q1 = W2 + (4*lane+1) * H2;
    const float* q2 = W2 + (4*lane+2) * H2;
    const float* q3 = W2 + (4*lane+3) * H2;
#pragma unroll
    for (int j = 0; j < H2; ++j)
        acc[j] = x0 * q0[j] + x1 * q1[j] + x2 * q2[j] + x3 * q3[j];
    // shuffle-tree reduce, splitting feature ownership each step
    float p16[16];
#pragma unroll
    for (int j = 0; j < 16; ++j) p16[j] = __shfl_xor(acc[j], 1);
    float r8[8];
    if (lane & 1) {
#pragma unroll
        for (int j = 0; j < 8; ++j) r8[j] = acc[8+j] + p16[8+j];
    } else {
#pragma unroll
        for (int j = 0; j < 8; ++j) r8[j] = acc[j] + p16[j];
    }
    float p8[8];
#pragma unroll
    for (int j = 0; j < 8; ++j) p8[j] = __shfl_xor(r8[j], 2);
    float r4[4];
    if (lane & 2) {
#pragma unroll
        for (int j = 0; j < 4; ++j) r4[j] = r8[4+j] + p8[4+j];
    } else {
#pragma unroll
        for (int j = 0; j < 4; ++j) r4[j] = r8[j] + p8[j];
    }
    float p4[4];
#pragma unroll
    for (int j = 0; j < 4; ++j) p4[j] = __shfl_xor(r4[j], 4);
    float r2[2];
    if (lane & 4) {
        r2[0] = r4[2] + p4[2]; r2[1] = r4[3] + p4[3];
    } else {
        r2[0] = r4[0] + p4[0]; r2[1] = r4[1] + p4[1];
    }
    int fb = ((lane & 1) << 3) | (((lane >> 1) & 1) << 2) | (((lane >> 2) & 1) << 1);
    // layer-2 src-side norm pre-applied; feats fb, fb+1 -> one half2
    ((__half2*)h2s)[(size_t)node * 8 + (fb >> 1)] =
        __floats2half2_rn(r2[0] * di, r2[1] * di);
}

// ---- fused gather2 + bias/relu + mean-pool ---------------------------------
// 8 lanes/node, 2 feats (4B fp16 granule) each; chunk-8 MLP; sorted batch ->
// wave (8 nodes) usually one graph: butterfly reduce, 16+1 atomics/wave.
__global__ void k_gB(const int* __restrict__ start_g, const int* __restrict__ cnt_g,
                     const int* __restrict__ esrc, const __half* __restrict__ h2s,
                     const float* __restrict__ b2, const float* __restrict__ dinv,
                     const int* __restrict__ batch,
                     float* __restrict__ psum, float* __restrict__ pcnt) {
    int t = blockIdx.x * 256 + threadIdx.x;
    int node = t >> 3;            // grid sized exactly
    int lane = t & 7;
    int beg = start_g[node];
    int cnt = cnt_g[node];
    const unsigned* base = (const unsigned*)h2s;   // 4B granules, row = 8
    float2 a = cvt42(base[(size_t)node * 8 + lane]);   // self loop
    int nfull = cnt >> 3;
    int rem = cnt & 7;
    int ev = (nfull > 0) ? esrc[beg + lane]
           : ((lane < rem) ? esrc[beg + lane] : 0);
    for (int c = 0; c < nfull; ++c) {
        int evn = 0;
        if (c + 1 < nfull) evn = esrc[beg + (c + 1) * 8 + lane];
        else if (lane < rem) evn = esrc[beg + nfull * 8 + lane];
        unsigned u0 = base[(size_t)__shfl(ev, 0, 8) * 8 + lane];
        unsigned u1 = base[(size_t)__shfl(ev, 1, 8) * 8 + lane];
        unsigned u2 = base[(size_t)__shfl(ev, 2, 8) * 8 + lane];
        unsigned u3 = base[(size_t)__shfl(ev, 3, 8) * 8 + lane];
        unsigned u4 = base[(size_t)__shfl(ev, 4, 8) * 8 + lane];
        unsigned u5 = base[(size_t)__shfl(ev, 5, 8) * 8 + lane];
        unsigned u6 = base[(size_t)__shfl(ev, 6, 8) * 8 + lane];
        unsigned u7 = base[(size_t)__shfl(ev, 7, 8) * 8 + lane];
        float2 v0 = cvt42(u0), v1 = cvt42(u1), v2 = cvt42(u2), v3 = cvt42(u3);
        float2 v4 = cvt42(u4), v5 = cvt42(u5), v6 = cvt42(u6), v7 = cvt42(u7);
        a.x += ((v0.x + v1.x) + (v2.x + v3.x)) + ((v4.x + v5.x) + (v6.x + v7.x));
        a.y += ((v0.y + v1.y) + (v2.y + v3.y)) + ((v4.y + v5.y) + (v6.y + v7.y));
        ev = evn;
    }
    if (rem) {
#pragma unroll
        for (int j = 0; j < 8; ++j) {
            int sj = __shfl(ev, j, 8);
            bool val = (j < rem);
            float2 v = cvt42(base[(size_t)(val ? sj : node) * 8 + lane]);
            float m = val ? 1.0f : 0.0f;
            a.x += v.x * m; a.y += v.y * m;
        }
    }
    float di = dinv[node];
    float vx = fmaxf(a.x * di + b2[2*lane+0], 0.0f);
    float vy = fmaxf(a.y * di + b2[2*lane+1], 0.0f);
    float c = (lane == 0) ? 1.0f : 0.0f;
    int g = batch[node];
    int wl = threadIdx.x & 63;
    int g0 = __shfl(g, 0);
    bool uni = (__ballot(g == g0) == ~0ull);
    if (uni) {
#pragma unroll
        for (int m = 8; m <= 32; m <<= 1) {
            vx += __shfl_xor(vx, m);
            vy += __shfl_xor(vy, m);
            c  += __shfl_xor(c, m);
        }
        if (wl < 8) {
            unsafeAtomicAdd(&psum[g0 * H2 + 2*wl + 0], vx);
            unsafeAtomicAdd(&psum[g0 * H2 + 2*wl + 1], vy);
        }
        if (wl == 0) unsafeAtomicAdd(&pcnt[g0], c);
    } else {
        unsafeAtomicAdd(&psum[g * H2 + 2*lane + 0], vx);
        unsafeAtomicAdd(&psum[g * H2 + 2*lane + 1], vy);
        if (lane == 0) unsafeAtomicAdd(&pcnt[g], 1.0f);
    }
}

// ---- head: mean, fc, softmax ------------------------------------------------
__global__ void k_head(const float* __restrict__ psum, const float* __restrict__ pcnt,
                       const float* __restrict__ fcw, const float* __restrict__ fcb,
                       float* __restrict__ out) {
    int g = blockIdx.x * 256 + threadIdx.x;
    if (g >= N_GRAPHS) return;
    float inv = 1.0f / fmaxf(pcnt[g], 1.0f);
    float p[H2];
#pragma unroll
    for (int j = 0; j < H2; ++j) p[j] = psum[g * H2 + j] * inv;
    float lg[NCLS];
    float m = -1e30f;
#pragma unroll
    for (int c = 0; c < NCLS; ++c) {
        float s = fcb[c];
#pragma unroll
        for (int j = 0; j < H2; ++j) s += p[j] * fcw[j * NCLS + c];
        lg[c] = s;
        m = fmaxf(m, s);
    }
    float sum = 0.0f;
#pragma unroll
    for (int c = 0; c < NCLS; ++c) { lg[c] = expf(lg[c] - m); sum += lg[c]; }
    float is = 1.0f / sum;
#pragma unroll
    for (int c = 0; c < NCLS; ++c) out[g * NCLS + c] = lg[c] * is;
}

extern "C" void kernel_launch(void* const* d_in, const int* in_sizes, int n_in,
                              void* d_out, int out_size, void* d_ws, size_t ws_size,
                              hipStream_t stream) {
    const float* X   = (const float*)d_in[0];
    const int*   ei  = (const int*)d_in[1];
    const int*   bat = (const int*)d_in[2];
    const float* W1  = (const float*)d_in[3];
    const float* b1  = (const float*)d_in[4];
    const float* W2  = (const float*)d_in[5];
    const float* b2  = (const float*)d_in[6];
    const float* fcw = (const float*)d_in[7];
    const float* fcb = (const float*)d_in[8];
    float* out = (float*)d_out;

    const int* src = ei;
    const int* dst = ei + N_EDGES;

    char* ws = (char*)d_ws;
    int*    bcur  = (int*)ws;     ws += 512 * 4;
    int*    startg= (int*)ws;     ws += (size_t)N_NODES * 4;
    int*    cntg  = (int*)ws;     ws += (size_t)N_NODES * 4;
    float*  dinv  = (float*)ws;   ws += (size_t)N_NODES * 4;
    int*    esrc  = (int*)ws;     ws += (size_t)NBUCKET * CAP * 4;   // 16 MB, gapped CSR
    int*    ebkt  = (int*)ws;     ws += (size_t)NBUCKET * CAP * 4;   // 16 MB
    __half* h1s   = (__half*)ws;  ws += (size_t)N_NODES * H1 * 2;    // 6.4 MB fp16
    __half* h2s   = (__half*)ws;  ws += (size_t)N_NODES * H2 * 2;    // 3.2 MB fp16
    float*  psum  = (float*)ws;   ws += (size_t)N_GRAPHS * H2 * 4;
    float*  pcnt  = (float*)ws;

    int nbN = (N_NODES + 255) / 256;

    k_init  <<<32, 256, 0, stream>>>(bcur, psum, pcnt);
    k_bin   <<<NBINBLK, 512, 0, stream>>>(src, dst, bcur, ebkt);
    k_place3<<<NBUCKET, 256, 0, stream>>>(bcur, ebkt, startg, cntg, dinv, esrc);
    k_gemm1 <<<nbN, 256, 0, stream>>>(X, W1, dinv, h1s);
    k_gA    <<<(N_NODES * 8) / 256, 256, 0, stream>>>(startg, cntg, esrc, h1s, b1, W2, dinv, h2s);
    k_gB    <<<(N_NODES * 8) / 256, 256, 0, stream>>>(startg, cntg, esrc, h2s, b2, dinv, bat, psum, pcnt);
    k_head  <<<(N_GRAPHS + 255) / 256, 256, 0, stream>>>(psum, pcnt, fcw, fcb, out);
}